// Round 8
// baseline (219.774 us; speedup 1.0000x reference)
//
#include <hip/hip_runtime.h>
#include <math.h>

#define Bb 8
#define Nn 4096
#define Dd 768
#define PADDED 1024
#define D4 192        // Dd/4
#define P4 256        // PADDED/4
#define NCHUNK 128    // n-chunks for the mean reduction
#define ROWS (Nn / NCHUNK)   // 32 rows per chunk

typedef float floatx4 __attribute__((ext_vector_type(4)));   // native vec for nontemporal builtins

// ---------------- kernel 1a: partial column sums (no atomics) ----------------
// grid: Bb*NCHUNK = 1024 blocks, 192 threads. partial[k][b][d] in ws.
__global__ __launch_bounds__(192) void k_colsum_part(const float4* __restrict__ x4,
                                                     float* __restrict__ partial) {
    int bid = blockIdx.x;
    int b = bid >> 7;              // /NCHUNK
    int k = bid & (NCHUNK - 1);
    int t = threadIdx.x;           // 0..191
    const float4* p = x4 + ((size_t)(b * Nn + k * ROWS) * D4) + t;
    float4 acc = {0.f, 0.f, 0.f, 0.f};
#pragma unroll 8
    for (int r = 0; r < ROWS; ++r) {
        float4 v = p[(size_t)r * D4];
        acc.x += v.x; acc.y += v.y; acc.z += v.z; acc.w += v.w;
    }
    float4* dst = (float4*)(partial + ((size_t)k * Bb + b) * Dd) + t;
    *dst = acc;
}

// ---------------- kernel 1b: atomic fallback (tiny ws) ----------------
__global__ __launch_bounds__(192) void k_colsum_atomic(const float4* __restrict__ x4,
                                                       float* __restrict__ c_sum) {
    int bid = blockIdx.x;
    int b = bid >> 7;
    int k = bid & (NCHUNK - 1);
    int t = threadIdx.x;
    const float4* p = x4 + ((size_t)(b * Nn + k * ROWS) * D4) + t;
    float4 acc = {0.f, 0.f, 0.f, 0.f};
#pragma unroll 8
    for (int r = 0; r < ROWS; ++r) {
        float4 v = p[(size_t)r * D4];
        acc.x += v.x; acc.y += v.y; acc.z += v.z; acc.w += v.w;
    }
    float* cs = c_sum + b * Dd + t * 4;
    atomicAdd(cs + 0, acc.x);
    atomicAdd(cs + 1, acc.y);
    atomicAdd(cs + 2, acc.z);
    atomicAdd(cs + 3, acc.w);
}

// ------- kernel 2: chunk-reduce + WHT (in LDS) + weight + GEMV + sigmoid -------
// grid: dim3(12, Bb) = 96 blocks, 256 threads. Each block redundantly reduces
// its b's partials and redoes the (trivial) WHT; then computes 64 gate outputs
// with 4 lanes per d. src layout: [nchunks][Bb][Dd]; nchunks==1 for atomics path.
__global__ __launch_bounds__(256) void k_whtgate2(const float* __restrict__ src, int nchunks,
                                                  const float* __restrict__ wht_weight,
                                                  const float4* __restrict__ gw4,
                                                  const float* __restrict__ gate_b,
                                                  float* __restrict__ gate) {
    __shared__ float s[PADDED];
    int b  = blockIdx.y;
    int dc = blockIdx.x;          // 0..11
    int t  = threadIdx.x;         // 0..255

    // 1. chunk-reduce + mean for d = t, t+256, t+512 (768 = 3*256); coalesced.
    float acc0 = 0.f, acc1 = 0.f, acc2 = 0.f;
    const float* sp = src + (size_t)b * Dd;
#pragma unroll 4
    for (int k = 0; k < nchunks; ++k) {
        const float* row = sp + (size_t)k * Bb * Dd;
        acc0 += row[t];
        acc1 += row[t + 256];
        acc2 += row[t + 512];
    }
    s[t]       = acc0 * (1.0f / (float)Nn);
    s[t + 256] = acc1 * (1.0f / (float)Nn);
    s[t + 512] = acc2 * (1.0f / (float)Nn);
    s[t + 768] = 0.f;                         // zero-pad 768..1023
    __syncthreads();

    // 2. 10-stage WHT butterfly, 4 elements per thread.
    //    s_new[i] = (i&st) ? s[i^st]-s[i] : s[i]+s[i^st]
    for (int st = 1; st < PADDED; st <<= 1) {
        float a0 = s[t];        float p0 = s[t ^ st];
        float a1 = s[t + 256];  float p1 = s[(t + 256) ^ st];
        float a2 = s[t + 512];  float p2 = s[(t + 512) ^ st];
        float a3 = s[t + 768];  float p3 = s[(t + 768) ^ st];
        __syncthreads();
        s[t]       = ((t)       & st) ? (p0 - a0) : (a0 + p0);
        s[t + 256] = ((t + 256) & st) ? (p1 - a1) : (a1 + p1);
        s[t + 512] = ((t + 512) & st) ? (p2 - a2) : (a2 + p2);
        s[t + 768] = ((t + 768) & st) ? (p3 - a3) : (a3 + p3);
        __syncthreads();
    }

    // 3. scale by 1/1024 and wht_weight
    {
        const float sc = 1.0f / (float)PADDED;
        s[t]       *= sc * wht_weight[t];
        s[t + 256] *= sc * wht_weight[t + 256];
        s[t + 512] *= sc * wht_weight[t + 512];
        s[t + 768] *= sc * wht_weight[t + 768];
    }
    __syncthreads();

    // 4. gate: 64 d per block, 4 lanes per d (q = quarter of the 1024-dim dot).
    const float4* s4 = (const float4*)s;      // 256 float4
    int dl = t >> 2;                          // 0..63
    int q  = t & 3;                           // 0..3
    int d  = dc * 64 + dl;                    // 0..767
    const float4* w = gw4 + (size_t)d * P4 + q * 64;
    const float4* cs4 = s4 + q * 64;
    float a = 0.f;
#pragma unroll 8
    for (int seg = 0; seg < 64; ++seg) {
        float4 wv = w[seg];
        float4 cv = cs4[seg];                 // 4 distinct LDS addrs/wave -> broadcast
        a += wv.x * cv.x + wv.y * cv.y + wv.z * cv.z + wv.w * cv.w;
    }
    a += __shfl_xor(a, 1, 64);
    a += __shfl_xor(a, 2, 64);
    if (q == 0) {
        float z = a + gate_b[d];
        gate[b * Dd + d] = 1.0f / (1.0f + expf(-z));
    }
}

// ---------------- kernel 3: out = x * gate ----------------
// grid: Bb*256 = 2048 blocks, 192 threads; 16 rows per block, gate held in-register.
// Nontemporal stores keep x resident in L3 for this second read.
__global__ __launch_bounds__(192) void k_scale(const floatx4* __restrict__ x4,
                                               const floatx4* __restrict__ gate4,
                                               floatx4* __restrict__ out4) {
    int bid = blockIdx.x;
    int b = bid >> 8;              // /256
    int n0 = (bid & 255) * 16;
    int t = threadIdx.x;           // 0..191
    floatx4 g = gate4[b * D4 + t];
    size_t base = ((size_t)(b * Nn + n0) * D4) + t;
#pragma unroll
    for (int r = 0; r < 16; ++r) {
        floatx4 v = x4[base + (size_t)r * D4];
        floatx4 o = v * g;
        __builtin_nontemporal_store(o, &out4[base + (size_t)r * D4]);
    }
}

extern "C" void kernel_launch(void* const* d_in, const int* in_sizes, int n_in,
                              void* d_out, int out_size, void* d_ws, size_t ws_size,
                              hipStream_t stream) {
    const float* x          = (const float*)d_in[0];
    const float* wht_weight = (const float*)d_in[1];
    const float* gate_w     = (const float*)d_in[2];
    const float* gate_b     = (const float*)d_in[3];
    float* out = (float*)d_out;

    // ws layout (big path): partial [NCHUNK][Bb][Dd] | gate [Bb][Dd]
    size_t need_big = ((size_t)NCHUNK * Bb * Dd + (size_t)Bb * Dd) * 4;
    float* wsf = (float*)d_ws;

    if (ws_size >= need_big) {
        float* partial = wsf;
        float* gate = partial + (size_t)NCHUNK * Bb * Dd;
        k_colsum_part<<<Bb * NCHUNK, 192, 0, stream>>>((const float4*)x, partial);
        k_whtgate2<<<dim3(12, Bb), 256, 0, stream>>>(partial, NCHUNK, wht_weight,
                                                     (const float4*)gate_w, gate_b, gate);
        k_scale<<<Bb * 256, 192, 0, stream>>>((const floatx4*)x, (const floatx4*)gate, (floatx4*)out);
    } else {
        // tiny-ws fallback: atomics into c_sum
        float* c_sum = wsf;                       // Bb*Dd
        float* gate  = c_sum + (size_t)Bb * Dd;   // Bb*Dd
        (void)hipMemsetAsync(c_sum, 0, (size_t)Bb * Dd * sizeof(float), stream);
        k_colsum_atomic<<<Bb * NCHUNK, 192, 0, stream>>>((const float4*)x, c_sum);
        k_whtgate2<<<dim3(12, Bb), 256, 0, stream>>>(c_sum, 1, wht_weight,
                                                     (const float4*)gate_w, gate_b, gate);
        k_scale<<<Bb * 256, 192, 0, stream>>>((const floatx4*)x, (const floatx4*)gate, (floatx4*)out);
    }
}

// Round 9
// 213.713 us; speedup vs baseline: 1.0284x; 1.0284x over previous
//
#include <hip/hip_runtime.h>
#include <math.h>

#define Bb 8
#define Nn 4096
#define Dd 768
#define PADDED 1024
#define D4 192        // Dd/4
#define P4 256        // PADDED/4
#define NCHUNK 128    // n-chunks for the mean reduction
#define ROWS (Nn / NCHUNK)   // 32 rows per chunk

typedef float floatx4 __attribute__((ext_vector_type(4)));   // native vec for nontemporal builtins

// ---------------- kernel 1a: partial column sums (no atomics) ----------------
// grid: Bb*NCHUNK = 1024 blocks, 192 threads. partial[k][b][d] in ws.
__global__ __launch_bounds__(192) void k_colsum_part(const float4* __restrict__ x4,
                                                     float* __restrict__ partial) {
    int bid = blockIdx.x;
    int b = bid >> 7;              // /NCHUNK
    int k = bid & (NCHUNK - 1);
    int t = threadIdx.x;           // 0..191
    const float4* p = x4 + ((size_t)(b * Nn + k * ROWS) * D4) + t;
    float4 acc = {0.f, 0.f, 0.f, 0.f};
#pragma unroll 8
    for (int r = 0; r < ROWS; ++r) {
        float4 v = p[(size_t)r * D4];
        acc.x += v.x; acc.y += v.y; acc.z += v.z; acc.w += v.w;
    }
    float4* dst = (float4*)(partial + ((size_t)k * Bb + b) * Dd) + t;
    *dst = acc;
}

// ---------------- kernel 1b: atomic fallback (tiny ws) ----------------
__global__ __launch_bounds__(192) void k_colsum_atomic(const float4* __restrict__ x4,
                                                       float* __restrict__ c_sum) {
    int bid = blockIdx.x;
    int b = bid >> 7;
    int k = bid & (NCHUNK - 1);
    int t = threadIdx.x;
    const float4* p = x4 + ((size_t)(b * Nn + k * ROWS) * D4) + t;
    float4 acc = {0.f, 0.f, 0.f, 0.f};
#pragma unroll 8
    for (int r = 0; r < ROWS; ++r) {
        float4 v = p[(size_t)r * D4];
        acc.x += v.x; acc.y += v.y; acc.z += v.z; acc.w += v.w;
    }
    float* cs = c_sum + b * Dd + t * 4;
    atomicAdd(cs + 0, acc.x);
    atomicAdd(cs + 1, acc.y);
    atomicAdd(cs + 2, acc.z);
    atomicAdd(cs + 3, acc.w);
}

// ------------- kernel 2: reduce chunks + WHT + weight -> cw[Bb][PADDED] -------------
// grid: Bb blocks, PADDED(=1024) threads.
// src layout: [nchunks][Bb][Dd]; nchunks==1 for the atomic path.
__global__ __launch_bounds__(PADDED) void k_wht(const float* __restrict__ src, int nchunks,
                                                const float* __restrict__ wht_weight,
                                                float* __restrict__ cw) {
    __shared__ float s[PADDED];
    int b = blockIdx.x;
    int t = threadIdx.x;
    float v = 0.f;
    if (t < Dd) {
        float acc = 0.f;
#pragma unroll 8
        for (int k = 0; k < nchunks; ++k)
            acc += src[((size_t)k * Bb + b) * Dd + t];
        v = acc * (1.0f / (float)Nn);   // mean
    }
    s[t] = v;                            // zero-pad 768..1023
    __syncthreads();
    // 10-stage butterfly; matches the reference's reshape/stack ordering:
    //   bit clear: self + partner(t+st);  bit set: partner(t-st) - self
    for (int st = 1; st < PADDED; st <<= 1) {
        float a = s[t];
        float p = s[t ^ st];
        __syncthreads();
        s[t] = (t & st) ? (p - a) : (a + p);
        __syncthreads();
    }
    cw[b * PADDED + t] = s[t] * (1.0f / (float)PADDED) * wht_weight[t];
}

// ------------- kernel 3: gate = sigmoid(cw @ gate_w.T + gate_b) -------------
// grid: 1536 blocks x 256 threads = 6144 waves; ONE WAVE PER OUTPUT (b,d).
// Each wave: 4 coalesced float4 loads/lane from gate_w row + 4 from cw row
// (8 independent loads in flight), shfl_xor tree reduce, sigmoid, 1 store.
__global__ __launch_bounds__(256) void k_gate(const float4* __restrict__ cw4,
                                              const float4* __restrict__ gw4,
                                              const float* __restrict__ gate_b,
                                              float* __restrict__ gate) {
    int wave = (blockIdx.x * 256 + threadIdx.x) >> 6;   // 0..6143
    int lane = threadIdx.x & 63;
    int d = wave >> 3;        // 0..767
    int b = wave & 7;         // 0..7
    const float4* w = gw4 + (size_t)d * P4;
    const float4* c = cw4 + (size_t)b * P4;
    float acc = 0.f;
#pragma unroll
    for (int j = 0; j < 4; ++j) {
        int seg = lane + 64 * j;
        float4 wv = w[seg];
        float4 cv = c[seg];
        acc += wv.x * cv.x + wv.y * cv.y + wv.z * cv.z + wv.w * cv.w;
    }
#pragma unroll
    for (int off = 32; off > 0; off >>= 1)
        acc += __shfl_xor(acc, off, 64);
    if (lane == 0) {
        float z = acc + gate_b[d];
        gate[b * Dd + d] = 1.0f / (1.0f + expf(-z));
    }
}

// ---------------- kernel 4: out = x * gate ----------------
// grid: Bb*256 = 2048 blocks, 192 threads; 16 rows per block, gate held in-register.
// Nontemporal stores keep x resident in L3 for this second read.
__global__ __launch_bounds__(192) void k_scale(const floatx4* __restrict__ x4,
                                               const floatx4* __restrict__ gate4,
                                               floatx4* __restrict__ out4) {
    int bid = blockIdx.x;
    int b = bid >> 8;              // /256
    int n0 = (bid & 255) * 16;
    int t = threadIdx.x;           // 0..191
    floatx4 g = gate4[b * D4 + t];
    size_t base = ((size_t)(b * Nn + n0) * D4) + t;
#pragma unroll
    for (int r = 0; r < 16; ++r) {
        floatx4 v = x4[base + (size_t)r * D4];
        floatx4 o = v * g;
        __builtin_nontemporal_store(o, &out4[base + (size_t)r * D4]);
    }
}

extern "C" void kernel_launch(void* const* d_in, const int* in_sizes, int n_in,
                              void* d_out, int out_size, void* d_ws, size_t ws_size,
                              hipStream_t stream) {
    const float* x          = (const float*)d_in[0];
    const float* wht_weight = (const float*)d_in[1];
    const float* gate_w     = (const float*)d_in[2];
    const float* gate_b     = (const float*)d_in[3];
    float* out = (float*)d_out;

    // ws layout (big path): partial [NCHUNK][Bb][Dd] | cw [Bb][PADDED] | gate [Bb][Dd]
    size_t need_big = ((size_t)NCHUNK * Bb * Dd + (size_t)Bb * PADDED + (size_t)Bb * Dd) * 4;
    float* wsf = (float*)d_ws;

    if (ws_size >= need_big) {
        float* partial = wsf;
        float* cw   = partial + (size_t)NCHUNK * Bb * Dd;
        float* gate = cw + (size_t)Bb * PADDED;
        k_colsum_part<<<Bb * NCHUNK, 192, 0, stream>>>((const float4*)x, partial);
        k_wht<<<Bb, PADDED, 0, stream>>>(partial, NCHUNK, wht_weight, cw);
        k_gate<<<1536, 256, 0, stream>>>((const float4*)cw, (const float4*)gate_w, gate_b, gate);
        k_scale<<<Bb * 256, 192, 0, stream>>>((const floatx4*)x, (const floatx4*)gate, (floatx4*)out);
    } else {
        // tiny-ws fallback: atomics into c_sum
        float* c_sum = wsf;                       // Bb*Dd
        float* cw    = c_sum + (size_t)Bb * Dd;   // Bb*PADDED
        float* gate  = cw + (size_t)Bb * PADDED;  // Bb*Dd
        (void)hipMemsetAsync(c_sum, 0, (size_t)Bb * Dd * sizeof(float), stream);
        k_colsum_atomic<<<Bb * NCHUNK, 192, 0, stream>>>((const float4*)x, c_sum);
        k_wht<<<Bb, PADDED, 0, stream>>>(c_sum, 1, wht_weight, cw);
        k_gate<<<1536, 256, 0, stream>>>((const float4*)cw, (const float4*)gate_w, gate_b, gate);
        k_scale<<<Bb * 256, 192, 0, stream>>>((const floatx4*)x, (const floatx4*)gate, (floatx4*)out);
    }
}